// Round 4
// baseline (751.733 us; speedup 1.0000x reference)
//
#include <hip/hip_runtime.h>

typedef unsigned short u16;
typedef unsigned int u32;

#define Bn 32
#define Cn 64
#define Hn 128
#define Wn 128
#define QD 8
#define HWn (Hn*Wn)
#define NEGV (-1e4f)

__device__ __forceinline__ float bf2f(u16 u){
  u32 i = ((u32)u) << 16; float f; __builtin_memcpy(&f, &i, 4); return f;
}
__device__ __forceinline__ u16 f2bf(float f){
  u32 i; __builtin_memcpy(&i, &f, 4);
  return (u16)((i + 0x7FFFu + ((i >> 16) & 1u)) >> 16);
}
__device__ __forceinline__ float softplusf(float x){
  return fmaxf(x, 0.0f) + log1pf(expf(-fabsf(x)));
}

// ---------------------------------------------------------------------------
// dtype detector: bits 8..15 of a dword are a bf16 sign/exp byte if the buffer
// is packed bf16 (concentrated near 0x38..0x40 | sign), uniform if f32 mantissa.
__global__ void k_detect(const u32* __restrict__ wq_raw, int* __restrict__ flag){
  __shared__ int cnt;
  if (threadIdx.x == 0) cnt = 0;
  __syncthreads();
  int local = 0;
  for (int i = threadIdx.x; i < 256; i += 64){   // 256 dwords = 1KB, safe for both dtypes
    u32 d = wq_raw[i];
    u32 m = (d >> 8) & 0x7Fu;                     // drop sign bit
    if (m >= 0x38u && m <= 0x40u) local++;
  }
  atomicAdd(&cnt, local);
  __syncthreads();
  if (threadIdx.x == 0) flag[0] = (cnt >= 128) ? 1 : 0;
}

// ---------------------------------------------------------------------------
// Convert weights to f32, transposed to [c][80]: 0..7 wq, 8..15 wk, 16..79 wv.
__device__ __forceinline__ float rd_any(const void* p, int i, bool bf){
  return bf ? bf2f(((const u16*)p)[i]) : ((const float*)p)[i];
}

__global__ void k_wconv(const void* wq, const void* bq, const void* wk, const void* bk,
                        const void* wv, const void* bv, const void* gamma,
                        const int* __restrict__ flag,
                        float* __restrict__ Wall, float* __restrict__ biasv,
                        float* __restrict__ gammaF){
  bool bf = flag[0] != 0;
  int t = threadIdx.x;
  for (int idx = t; idx < Cn*80; idx += 256){
    int c = idx / 80, j = idx % 80;
    float v;
    if (j < 8)       v = rd_any(wq, j*Cn + c, bf);
    else if (j < 16) v = rd_any(wk, (j-8)*Cn + c, bf);
    else             v = rd_any(wv, (j-16)*Cn + c, bf);
    Wall[idx] = v;
  }
  for (int j = t; j < 80; j += 256){
    float v = (j < 8) ? rd_any(bq, j, bf) : (j < 16) ? rd_any(bk, j-8, bf) : rd_any(bv, j-16, bf);
    biasv[j] = v;
  }
  if (t == 0) gammaF[0] = rd_any(gamma, 0, bf);
}

// ---------------------------------------------------------------------------
// Projection: per-pixel 80-output 1x1 conv. Q,K -> softplus f32; V -> bf16.
template<bool BF>
__device__ __forceinline__ void proj_impl(const void* __restrict__ xin,
    const float* __restrict__ Wall, const float* __restrict__ biasv,
    float* __restrict__ Qf, float* __restrict__ Kf, u16* __restrict__ Vb){
  int b = blockIdx.x >> 6;                       // 64 blocks per batch (16384/256)
  int p = (blockIdx.x & 63)*256 + threadIdx.x;   // pixel index in [0,HW)
  float accQ[QD], accK[QD], accV[Cn];
  #pragma unroll
  for (int j=0;j<QD;j++){ accQ[j]=biasv[j]; accK[j]=biasv[QD+j]; }
  #pragma unroll
  for (int j=0;j<Cn;j++) accV[j]=biasv[16+j];
  size_t xoff = (size_t)b*Cn*HWn + p;
  for (int c=0;c<Cn;c++){
    float xv = BF ? bf2f(((const u16*)xin)[xoff + (size_t)c*HWn])
                  : ((const float*)xin)[xoff + (size_t)c*HWn];
    const float* wc = Wall + c*80;               // uniform -> scalar loads
    #pragma unroll
    for (int j=0;j<QD;j++) accQ[j] = fmaf(xv, wc[j], accQ[j]);
    #pragma unroll
    for (int j=0;j<QD;j++) accK[j] = fmaf(xv, wc[QD+j], accK[j]);
    #pragma unroll
    for (int j=0;j<Cn;j++) accV[j] = fmaf(xv, wc[16+j], accV[j]);
  }
  size_t qbase = (size_t)b*QD*HWn + p;
  #pragma unroll
  for (int j=0;j<QD;j++){
    Qf[qbase + (size_t)j*HWn] = softplusf(accQ[j]);
    Kf[qbase + (size_t)j*HWn] = softplusf(accK[j]);
  }
  size_t vbase = (size_t)b*Cn*HWn + p;
  #pragma unroll
  for (int j=0;j<Cn;j++) Vb[vbase + (size_t)j*HWn] = f2bf(accV[j]);
}

__global__ __launch_bounds__(256) void k_proj(const void* __restrict__ xin,
    const int* __restrict__ flag, const float* __restrict__ Wall,
    const float* __restrict__ biasv, float* __restrict__ Qf,
    float* __restrict__ Kf, u16* __restrict__ Vb){
  if (flag[0]) proj_impl<true >(xin, Wall, biasv, Qf, Kf, Vb);
  else         proj_impl<false>(xin, Wall, biasv, Qf, Kf, Vb);
}

// ---------------------------------------------------------------------------
// Mcol[b,c,q,w] = sum_h V[b,c,h,w] * K[b,q,h,w]. Block=(b, c-tile of 4), thread=(w, 2c).
__global__ __launch_bounds__(256) void k_mcol(const u16* __restrict__ Vb,
    const float* __restrict__ Kf, float* __restrict__ Mcol){
  int b = blockIdx.x >> 4; int ct = blockIdx.x & 15;
  int w = threadIdx.x & 127; int cs = (threadIdx.x >> 7)*2;
  int c0 = ct*4 + cs;
  const u16* vp = Vb + ((size_t)b*Cn + c0)*HWn + w;
  const float* kp = Kf + (size_t)b*QD*HWn + w;
  float acc0[QD], acc1[QD];
  #pragma unroll
  for (int q=0;q<QD;q++){ acc0[q]=0.f; acc1[q]=0.f; }
  for (int h=0; h<Hn; h++){
    float v0 = bf2f(vp[h*Wn]);
    float v1 = bf2f(vp[HWn + h*Wn]);
    #pragma unroll
    for (int q=0;q<QD;q++){
      float k = kp[(size_t)q*HWn + h*Wn];
      acc0[q] = fmaf(v0, k, acc0[q]);
      acc1[q] = fmaf(v1, k, acc1[q]);
    }
  }
  #pragma unroll
  for (int q=0;q<QD;q++){
    Mcol[(((size_t)b*Cn + c0  )*QD + q)*Wn + w] = acc0[q];
    Mcol[(((size_t)b*Cn + c0+1)*QD + q)*Wn + w] = acc1[q];
  }
}

// ---------------------------------------------------------------------------
// Mrow[b,c,q,h] = sum_w V[b,c,h,w] * K[b,q,h,w]. Block=(b, c-tile of 4), thread=(h, 2c).
__global__ __launch_bounds__(256) void k_mrow(const u16* __restrict__ Vb,
    const float* __restrict__ Kf, float* __restrict__ Mrow){
  int b = blockIdx.x >> 4; int ct = blockIdx.x & 15;
  int h = threadIdx.x & 127; int cs = (threadIdx.x >> 7)*2;
  int c0 = ct*4 + cs;
  const u32* vp0 = (const u32*)(Vb + ((size_t)b*Cn + c0  )*HWn + (size_t)h*Wn);
  const u32* vp1 = (const u32*)(Vb + ((size_t)b*Cn + c0+1)*HWn + (size_t)h*Wn);
  const float2* kp = (const float2*)(Kf + (size_t)b*QD*HWn + (size_t)h*Wn);
  float acc0[QD], acc1[QD];
  #pragma unroll
  for (int q=0;q<QD;q++){ acc0[q]=0.f; acc1[q]=0.f; }
  for (int i=0;i<Wn/2;i++){
    u32 u0 = vp0[i], u1 = vp1[i];
    float v00 = bf2f((u16)u0), v01 = bf2f((u16)(u0>>16));
    float v10 = bf2f((u16)u1), v11 = bf2f((u16)(u1>>16));
    #pragma unroll
    for (int q=0;q<QD;q++){
      float2 k = kp[(size_t)q*(HWn/2) + i];
      acc0[q] = fmaf(v00, k.x, fmaf(v01, k.y, acc0[q]));
      acc1[q] = fmaf(v10, k.x, fmaf(v11, k.y, acc1[q]));
    }
  }
  #pragma unroll
  for (int q=0;q<QD;q++){
    Mrow[(((size_t)b*Cn + c0  )*QD + q)*Hn + h] = acc0[q];
    Mrow[(((size_t)b*Cn + c0+1)*QD + q)*Hn + h] = acc1[q];
  }
}

// ---------------------------------------------------------------------------
// Final: out = gamma*( sum_q Q[q,h,w]*(Mcol[c,q,w]+Mrow[c,q,h]) - 1e4*V[c,h,w] ) + x
// Block=(b, h-tile of 8), 256 threads = (w 0..127, s 0..1); thread does 4 h x 64 c.
template<bool BF>
__device__ __forceinline__ void final_impl(const void* __restrict__ xin,
    const float* __restrict__ Qf, const u16* __restrict__ Vb,
    const float* __restrict__ Mcol, const float* __restrict__ Mrow,
    const float* __restrict__ gammaF, void* __restrict__ outp, float* mr){
  int b = blockIdx.x >> 4;
  int ht = blockIdx.x & 15;
  int w = threadIdx.x & 127;
  int s = threadIdx.x >> 7;
  int h0 = ht*8;
  float gma = gammaF[0];
  // stage Mrow[b, :, :, h0..h0+7] into LDS as [c][hl][q]
  for (int idx = threadIdx.x; idx < Cn*8*QD; idx += 256){
    int c = idx >> 6; int rem = idx & 63; int q = rem >> 3; int hl = rem & 7;
    mr[(c*8 + hl)*QD + q] = Mrow[(((size_t)b*Cn + c)*QD + q)*Hn + h0 + hl];
  }
  __syncthreads();
  float Qr[4][QD];
  #pragma unroll
  for (int i=0;i<4;i++){
    int h = h0 + s*4 + i;
    #pragma unroll
    for (int q=0;q<QD;q++)
      Qr[i][q] = Qf[(((size_t)b*QD + q)*Hn + h)*Wn + w];
  }
  for (int c=0;c<Cn;c++){
    float Mc[QD];
    #pragma unroll
    for (int q=0;q<QD;q++)
      Mc[q] = Mcol[(((size_t)b*Cn + c)*QD + q)*Wn + w];
    size_t base = ((size_t)b*Cn + c)*HWn + (size_t)h0*Wn + w;
    #pragma unroll
    for (int i=0;i<4;i++){
      int hl = s*4 + i;
      size_t off = base + (size_t)hl*Wn;
      float v = bf2f(Vb[off]);
      float acc = NEGV * v;
      #pragma unroll
      for (int q=0;q<QD;q++)
        acc = fmaf(Qr[i][q], Mc[q] + mr[(c*8 + hl)*QD + q], acc);
      float xv = BF ? bf2f(((const u16*)xin)[off]) : ((const float*)xin)[off];
      float res = fmaf(gma, acc, xv);
      if (BF) ((u16*)outp)[off] = f2bf(res);
      else    ((float*)outp)[off] = res;
    }
  }
}

__global__ __launch_bounds__(256) void k_final(const void* __restrict__ xin,
    const int* __restrict__ flag, const float* __restrict__ Qf,
    const u16* __restrict__ Vb, const float* __restrict__ Mcol,
    const float* __restrict__ Mrow, const float* __restrict__ gammaF,
    void* __restrict__ outp){
  __shared__ float mr[Cn*8*QD];
  if (flag[0]) final_impl<true >(xin, Qf, Vb, Mcol, Mrow, gammaF, outp, mr);
  else         final_impl<false>(xin, Qf, Vb, Mcol, Mrow, gammaF, outp, mr);
}

// ---------------------------------------------------------------------------
extern "C" void kernel_launch(void* const* d_in, const int* in_sizes, int n_in,
                              void* d_out, int out_size, void* d_ws, size_t ws_size,
                              hipStream_t stream){
  char* ws = (char*)d_ws;
  // workspace layout (bytes):
  float* Qf     = (float*)(ws);                        // 16,777,216
  float* Kf     = (float*)(ws + 16777216);             // 16,777,216
  float* Mcol   = (float*)(ws + 33554432);             //  8,388,608
  float* Mrow   = (float*)(ws + 41943040);             //  8,388,608
  float* Wall   = (float*)(ws + 50331648);             //     20,480
  float* biasv  = (float*)(ws + 50331648 + 20480);     //        320
  float* gammaF = (float*)(ws + 50331648 + 20800);     //          4
  int*   flag   = (int*)  (ws + 50331648 + 20804);     //          4
  u16*   Vb     = (u16*)  (ws + 50352640);             // 67,108,864 (ends ~117.5MB)

  k_detect<<<1, 64, 0, stream>>>((const u32*)d_in[1], flag);
  k_wconv<<<1, 256, 0, stream>>>(d_in[1], d_in[2], d_in[3], d_in[4],
                                 d_in[5], d_in[6], d_in[7], flag,
                                 Wall, biasv, gammaF);
  k_proj<<<Bn*(HWn/256), 256, 0, stream>>>(d_in[0], flag, Wall, biasv, Qf, Kf, Vb);
  k_mcol<<<Bn*16, 256, 0, stream>>>(Vb, Kf, Mcol);
  k_mrow<<<Bn*16, 256, 0, stream>>>(Vb, Kf, Mrow);
  k_final<<<Bn*16, 256, 0, stream>>>(d_in[0], flag, Qf, Vb, Mcol, Mrow, gammaF, d_out);
}

// Round 5
// 483.686 us; speedup vs baseline: 1.5542x; 1.5542x over previous
//
#include <hip/hip_runtime.h>

typedef unsigned short u16;
typedef unsigned int u32;

#define Bn 32
#define Cn 64
#define Hn 128
#define Wn 128
#define QD 8
#define HWn (Hn*Wn)
#define NEGV (-1e4f)

__device__ __forceinline__ float bf2f(u16 u){
  u32 i = ((u32)u) << 16; float f; __builtin_memcpy(&f, &i, 4); return f;
}
__device__ __forceinline__ float bfLO(u32 x){
  u32 i = x << 16; float f; __builtin_memcpy(&f, &i, 4); return f;
}
__device__ __forceinline__ float bfHI(u32 x){
  u32 i = x & 0xFFFF0000u; float f; __builtin_memcpy(&f, &i, 4); return f;
}
__device__ __forceinline__ u16 f2bf(float f){
  u32 i; __builtin_memcpy(&i, &f, 4);
  return (u16)((i + 0x7FFFu + ((i >> 16) & 1u)) >> 16);
}
__device__ __forceinline__ float softplusf(float x){
  return fmaxf(x, 0.0f) + log1pf(expf(-fabsf(x)));
}

// ---------------------------------------------------------------------------
// dtype detector: bits 8..15 of a dword are a bf16 sign/exp byte if the buffer
// is packed bf16 (concentrated near 0x38..0x40 | sign), uniform if f32 mantissa.
__global__ void k_detect(const u32* __restrict__ wq_raw, int* __restrict__ flag){
  __shared__ int cnt;
  if (threadIdx.x == 0) cnt = 0;
  __syncthreads();
  int local = 0;
  for (int i = threadIdx.x; i < 256; i += 64){
    u32 d = wq_raw[i];
    u32 m = (d >> 8) & 0x7Fu;
    if (m >= 0x38u && m <= 0x40u) local++;
  }
  atomicAdd(&cnt, local);
  __syncthreads();
  if (threadIdx.x == 0) flag[0] = (cnt >= 128) ? 1 : 0;
}

// ---------------------------------------------------------------------------
// Convert weights to f32, transposed to [c][80]: 0..7 wq, 8..15 wk, 16..79 wv.
__device__ __forceinline__ float rd_any(const void* p, int i, bool bf){
  return bf ? bf2f(((const u16*)p)[i]) : ((const float*)p)[i];
}

__global__ void k_wconv(const void* wq, const void* bq, const void* wk, const void* bk,
                        const void* wv, const void* bv, const void* gamma,
                        const int* __restrict__ flag,
                        float* __restrict__ Wall, float* __restrict__ biasv,
                        float* __restrict__ gammaF){
  bool bf = flag[0] != 0;
  int t = threadIdx.x;
  for (int idx = t; idx < Cn*80; idx += 256){
    int c = idx / 80, j = idx % 80;
    float v;
    if (j < 8)       v = rd_any(wq, j*Cn + c, bf);
    else if (j < 16) v = rd_any(wk, (j-8)*Cn + c, bf);
    else             v = rd_any(wv, (j-16)*Cn + c, bf);
    Wall[idx] = v;
  }
  for (int j = t; j < 80; j += 256){
    float v = (j < 8) ? rd_any(bq, j, bf) : (j < 16) ? rd_any(bk, j-8, bf) : rd_any(bv, j-16, bf);
    biasv[j] = v;
  }
  if (t == 0) gammaF[0] = rd_any(gamma, 0, bf);
}

// ---------------------------------------------------------------------------
// Projection: per-pixel 80-output 1x1 conv. Q -> f32; K,V -> bf16.
template<bool BF>
__device__ __forceinline__ void proj_impl(const void* __restrict__ xin,
    const float* __restrict__ Wall, const float* __restrict__ biasv,
    float* __restrict__ Qf, u16* __restrict__ Kb, u16* __restrict__ Vb){
  int b = blockIdx.x >> 6;
  int p = (blockIdx.x & 63)*256 + threadIdx.x;
  float accQ[QD], accK[QD], accV[Cn];
  #pragma unroll
  for (int j=0;j<QD;j++){ accQ[j]=biasv[j]; accK[j]=biasv[QD+j]; }
  #pragma unroll
  for (int j=0;j<Cn;j++) accV[j]=biasv[16+j];
  size_t xoff = (size_t)b*Cn*HWn + p;
  for (int c=0;c<Cn;c++){
    float xv = BF ? bf2f(((const u16*)xin)[xoff + (size_t)c*HWn])
                  : ((const float*)xin)[xoff + (size_t)c*HWn];
    const float* wc = Wall + c*80;               // uniform -> scalar loads
    #pragma unroll
    for (int j=0;j<QD;j++) accQ[j] = fmaf(xv, wc[j], accQ[j]);
    #pragma unroll
    for (int j=0;j<QD;j++) accK[j] = fmaf(xv, wc[QD+j], accK[j]);
    #pragma unroll
    for (int j=0;j<Cn;j++) accV[j] = fmaf(xv, wc[16+j], accV[j]);
  }
  size_t qbase = (size_t)b*QD*HWn + p;
  #pragma unroll
  for (int j=0;j<QD;j++){
    Qf[qbase + (size_t)j*HWn] = softplusf(accQ[j]);
    Kb[qbase + (size_t)j*HWn] = f2bf(softplusf(accK[j]));
  }
  size_t vbase = (size_t)b*Cn*HWn + p;
  #pragma unroll
  for (int j=0;j<Cn;j++) Vb[vbase + (size_t)j*HWn] = f2bf(accV[j]);
}

__global__ __launch_bounds__(256) void k_proj(const void* __restrict__ xin,
    const int* __restrict__ flag, const float* __restrict__ Wall,
    const float* __restrict__ biasv, float* __restrict__ Qf,
    u16* __restrict__ Kb, u16* __restrict__ Vb){
  if (flag[0]) proj_impl<true >(xin, Wall, biasv, Qf, Kb, Vb);
  else         proj_impl<false>(xin, Wall, biasv, Qf, Kb, Vb);
}

// ---------------------------------------------------------------------------
// Fused M-reduction. Block = (b, 4-channel tile), 256 threads, loop 8 h-tiles.
//   Mrow[b,c,q,h] = sum_w V[c,h,w]*K[q,h,w]   (completes per h-tile)
//   Mcol[b,c,q,w] = sum_h V[c,h,w]*K[q,h,w]   (register-accumulated, no atomics)
// LDS tiles bf16 with XOR-(h<<2) swizzle at 4-u16 granularity: row stride is
// 256B (bank-degenerate); the swizzle spreads the h-indexed column reads
// across banks while keeping 8B-aligned b64 reads (bits 0-1 untouched).
__global__ __launch_bounds__(256, 2) void k_msum(const u16* __restrict__ Vb,
    const u16* __restrict__ Kb, float* __restrict__ Mcol, float* __restrict__ Mrow){
  __shared__ u16 Kl[8*16*128];   // [q*16+h][w ^ (h<<2)]  32KB
  __shared__ u16 Vl[4*16*128];   // [c*16+h][w ^ (h<<2)]  16KB
  int b  = blockIdx.x >> 4;
  int ct = blockIdx.x & 15;
  int t  = threadIdx.x;
  float macc[16];
  #pragma unroll
  for (int i=0;i<16;i++) macc[i] = 0.f;
  const u32* kg = (const u32*)(Kb + (size_t)b*QD*HWn);
  const u32* vg = (const u32*)(Vb + ((size_t)b*Cn + ct*4)*HWn);

  for (int ht = 0; ht < Hn/16; ++ht){
    int h0 = ht*16;
    // ---- stage K tile: [8q][16h][64 u32], coalesced, 32 u32/thread
    #pragma unroll
    for (int r=0;r<32;r++){
      int f = r*256 + t;
      int q = f >> 10, h = (f >> 6) & 15, w2 = f & 63;
      u32 kv = kg[(size_t)q*(HWn/2) + (size_t)(h0+h)*(Wn/2) + w2];
      int wi = (w2*2) ^ (h<<2);
      *(u32*)&Kl[(q*16+h)*128 + wi] = kv;
    }
    // ---- stage V tile: [4c][16h][64 u32], coalesced, 16 u32/thread
    #pragma unroll
    for (int r=0;r<16;r++){
      int f = r*256 + t;
      int c = f >> 10, h = (f >> 6) & 15, w2 = f & 63;
      u32 vv = vg[(size_t)c*(HWn/2) + (size_t)(h0+h)*(Wn/2) + w2];
      int wi = (w2*2) ^ (h<<2);
      *(u32*)&Vl[(c*16+h)*128 + wi] = vv;
    }
    __syncthreads();
    // ---- Mrow: 512 outputs [c][q][h], 2/thread, logical-w walk (XOR/iter)
    #pragma unroll
    for (int r=0;r<2;r++){
      int idx = r*256 + t;
      int c = idx >> 7, q = (idx >> 4) & 7, h = idx & 15;
      const u16* kr = &Kl[(q*16+h)*128];
      const u16* vr = &Vl[(c*16+h)*128];
      int hs = h << 2;
      float acc = 0.f;
      #pragma unroll 8
      for (int w4=0; w4<32; ++w4){
        int wi = (w4<<2) ^ hs;
        u32 k0 = *(const u32*)&kr[wi];
        u32 k1 = *(const u32*)&kr[wi+2];
        u32 v0 = *(const u32*)&vr[wi];
        u32 v1 = *(const u32*)&vr[wi+2];
        acc = fmaf(bfLO(v0), bfLO(k0), acc);
        acc = fmaf(bfHI(v0), bfHI(k0), acc);
        acc = fmaf(bfLO(v1), bfLO(k1), acc);
        acc = fmaf(bfHI(v1), bfHI(k1), acc);
      }
      Mrow[(((size_t)b*Cn + ct*4 + c)*QD + q)*Hn + h0 + h] = acc;
    }
    // ---- Mcol partials: [c][q][w-quad], 4 quads/thread, h-reduction
    #pragma unroll
    for (int r=0;r<4;r++){
      int idx = r*256 + t;
      int c = idx >> 8, q = (idx >> 5) & 7, w4 = idx & 31;
      float a0 = macc[r*4], a1 = macc[r*4+1], a2 = macc[r*4+2], a3 = macc[r*4+3];
      #pragma unroll 4
      for (int h=0; h<16; ++h){
        int wi = ((w4 ^ h) << 2);            // (w4*4) ^ (h*4)
        const u16* kr = &Kl[(q*16+h)*128];
        const u16* vr = &Vl[(c*16+h)*128];
        u32 k0 = *(const u32*)&kr[wi];
        u32 k1 = *(const u32*)&kr[wi+2];
        u32 v0 = *(const u32*)&vr[wi];
        u32 v1 = *(const u32*)&vr[wi+2];
        a0 = fmaf(bfLO(v0), bfLO(k0), a0);
        a1 = fmaf(bfHI(v0), bfHI(k0), a1);
        a2 = fmaf(bfLO(v1), bfLO(k1), a2);
        a3 = fmaf(bfHI(v1), bfHI(k1), a3);
      }
      macc[r*4] = a0; macc[r*4+1] = a1; macc[r*4+2] = a2; macc[r*4+3] = a3;
    }
    __syncthreads();
  }
  // ---- write Mcol (coalesced float4)
  #pragma unroll
  for (int r=0;r<4;r++){
    int idx = r*256 + t;
    int c = idx >> 8, q = (idx >> 5) & 7, w4 = idx & 31;
    size_t o = (((size_t)b*Cn + ct*4 + c)*QD + q)*Wn + w4*4;
    float4 v; v.x = macc[r*4]; v.y = macc[r*4+1]; v.z = macc[r*4+2]; v.w = macc[r*4+3];
    *(float4*)&Mcol[o] = v;
  }
}

// ---------------------------------------------------------------------------
// Final: out = gamma*( sum_q Q[q,h,w]*(Mcol[c,q,w]+Mrow[c,q,h]) - 1e4*V[c,h,w] ) + x
template<bool BF>
__device__ __forceinline__ void final_impl(const void* __restrict__ xin,
    const float* __restrict__ Qf, const u16* __restrict__ Vb,
    const float* __restrict__ Mcol, const float* __restrict__ Mrow,
    const float* __restrict__ gammaF, void* __restrict__ outp, float* mr){
  int b = blockIdx.x >> 4;
  int ht = blockIdx.x & 15;
  int w = threadIdx.x & 127;
  int s = threadIdx.x >> 7;
  int h0 = ht*8;
  float gma = gammaF[0];
  for (int idx = threadIdx.x; idx < Cn*8*QD; idx += 256){
    int c = idx >> 6; int rem = idx & 63; int q = rem >> 3; int hl = rem & 7;
    mr[(c*8 + hl)*QD + q] = Mrow[(((size_t)b*Cn + c)*QD + q)*Hn + h0 + hl];
  }
  __syncthreads();
  float Qr[4][QD];
  #pragma unroll
  for (int i=0;i<4;i++){
    int h = h0 + s*4 + i;
    #pragma unroll
    for (int q=0;q<QD;q++)
      Qr[i][q] = Qf[(((size_t)b*QD + q)*Hn + h)*Wn + w];
  }
  for (int c=0;c<Cn;c++){
    float Mc[QD];
    #pragma unroll
    for (int q=0;q<QD;q++)
      Mc[q] = Mcol[(((size_t)b*Cn + c)*QD + q)*Wn + w];
    size_t base = ((size_t)b*Cn + c)*HWn + (size_t)h0*Wn + w;
    #pragma unroll
    for (int i=0;i<4;i++){
      int hl = s*4 + i;
      size_t off = base + (size_t)hl*Wn;
      float v = bf2f(Vb[off]);
      float acc = NEGV * v;
      #pragma unroll
      for (int q=0;q<QD;q++)
        acc = fmaf(Qr[i][q], Mc[q] + mr[(c*8 + hl)*QD + q], acc);
      float xv = BF ? bf2f(((const u16*)xin)[off]) : ((const float*)xin)[off];
      float res = fmaf(gma, acc, xv);
      if (BF) ((u16*)outp)[off] = f2bf(res);
      else    ((float*)outp)[off] = res;
    }
  }
}

__global__ __launch_bounds__(256) void k_final(const void* __restrict__ xin,
    const int* __restrict__ flag, const float* __restrict__ Qf,
    const u16* __restrict__ Vb, const float* __restrict__ Mcol,
    const float* __restrict__ Mrow, const float* __restrict__ gammaF,
    void* __restrict__ outp){
  __shared__ float mr[Cn*8*QD];
  if (flag[0]) final_impl<true >(xin, Qf, Vb, Mcol, Mrow, gammaF, outp, mr);
  else         final_impl<false>(xin, Qf, Vb, Mcol, Mrow, gammaF, outp, mr);
}

// ---------------------------------------------------------------------------
extern "C" void kernel_launch(void* const* d_in, const int* in_sizes, int n_in,
                              void* d_out, int out_size, void* d_ws, size_t ws_size,
                              hipStream_t stream){
  char* ws = (char*)d_ws;
  // workspace layout (bytes):
  float* Qf     = (float*)(ws);                        // 16,777,216
  u16*   Kb     = (u16*)  (ws + 16777216);             //  8,388,608 (bf16)
  float* Mcol   = (float*)(ws + 25165824);             //  8,388,608
  float* Mrow   = (float*)(ws + 33554432);             //  8,388,608
  float* Wall   = (float*)(ws + 41943040);             //     20,480
  float* biasv  = (float*)(ws + 41963520);             //        320
  float* gammaF = (float*)(ws + 41963840);             //          4
  int*   flag   = (int*)  (ws + 41963844);             //          4
  u16*   Vb     = (u16*)  (ws + 41964032);             // 67,108,864 (ends ~104MB)

  k_detect<<<1, 64, 0, stream>>>((const u32*)d_in[1], flag);
  k_wconv<<<1, 256, 0, stream>>>(d_in[1], d_in[2], d_in[3], d_in[4],
                                 d_in[5], d_in[6], d_in[7], flag,
                                 Wall, biasv, gammaF);
  k_proj<<<Bn*(HWn/256), 256, 0, stream>>>(d_in[0], flag, Wall, biasv, Qf, Kb, Vb);
  k_msum<<<Bn*16, 256, 0, stream>>>(Vb, Kb, Mcol, Mrow);
  k_final<<<Bn*16, 256, 0, stream>>>(d_in[0], flag, Qf, Vb, Mcol, Mrow, gammaF, d_out);
}